// Round 2
// baseline (8285.769 us; speedup 1.0000x reference)
//
#include <hip/hip_runtime.h>
#include <math.h>

typedef unsigned short u16;

#define DIMC 256
#define WC 64
#define DHC 32
#define HC 8
#define HIDC 1024

__device__ __forceinline__ float bf2f(u16 u){
  unsigned int i = ((unsigned int)u) << 16;
  float f;
  __builtin_memcpy(&f, &i, 4);
  return f;
}
__device__ __forceinline__ u16 f2bf(float f){
  unsigned int i;
  __builtin_memcpy(&i, &f, 4);
  i += 0x7FFFu + ((i >> 16) & 1u);
  return (u16)(i >> 16);
}
__device__ __forceinline__ ushort4 f4bf(float4 v){
  ushort4 r;
  r.x = f2bf(v.x); r.y = f2bf(v.y); r.z = f2bf(v.z); r.w = f2bf(v.w);
  return r;
}

// ---------------- K1: LayerNorm1 over all tokens (fp32 -> fp32 d_out) ----------------
__global__ __launch_bounds__(256) void k_ln1(const float* __restrict__ x,
                                             const float* __restrict__ g,
                                             const float* __restrict__ b,
                                             float* __restrict__ out, int ntok){
  const int lane = threadIdx.x & 63;
  const int wv = threadIdx.x >> 6;
  const long long t = (long long)blockIdx.x * 4 + wv;
  if (t >= ntok) return;
  float4 v = ((const float4*)(x + t * DIMC))[lane];
  float s = v.x + v.y + v.z + v.w;
  #pragma unroll
  for (int o = 32; o; o >>= 1) s += __shfl_xor(s, o);
  float mu = s * (1.0f/256.0f);
  float d0 = v.x-mu, d1 = v.y-mu, d2 = v.z-mu, d3 = v.w-mu;
  float q = d0*d0 + d1*d1 + d2*d2 + d3*d3;
  #pragma unroll
  for (int o = 32; o; o >>= 1) q += __shfl_xor(q, o);
  float rs = rsqrtf(q * (1.0f/256.0f) + 1e-5f);
  float4 gv = ((const float4*)g)[lane];
  float4 bv = ((const float4*)b)[lane];
  float4 ov;
  ov.x = d0*rs*gv.x + bv.x;
  ov.y = d1*rs*gv.y + bv.y;
  ov.z = d2*rs*gv.z + bv.z;
  ov.w = d3*rs*gv.w + bv.w;
  ((float4*)(out + t * DIMC))[lane] = ov;
}

// ------------- K2: per-window fused qkv + attention + proj + residual -------------
// Reads its window's X rows (fp32) from d_out, writes h (fp32) back over the same rows.
__global__ __launch_bounds__(256) void k_attn(const int* __restrict__ idx,
    const float* __restrict__ qkvw, const float* __restrict__ qkvb,
    const float* __restrict__ projw, const float* __restrict__ projb,
    float* __restrict__ Y){
  __shared__ __align__(16) u16 xs[WC*DIMC];                  // 32768 B (bf16 x-hat)
  __shared__ __align__(16) unsigned char qkvmem[3*WC*34*2];  // 13056 B (q,k,v rows padded to 34)
  __shared__ __align__(16) float Sb[WC*WC];                  // 16384 B, aliased as weight tile

  u16* qb = (u16*)qkvmem;
  u16* kb = qb + WC*34;
  u16* vb = kb + WC*34;
  float* Oh = (float*)qkvmem;   // 64x32 f32 (8192 B) overlaps q,k region, not v
  u16* wtile = (u16*)Sb;        // 8192 bf16 = 16 KB

  const int tid = threadIdx.x;
  const int lane = tid & 63;
  const int wv = tid >> 6;
  const int m = blockIdx.x;
  const long long row0 = (long long)idx[m] * (WC * DIMC);

  // load xs (64 x 256), fp32 global -> bf16 LDS
  {
    const float4* src = (const float4*)(Y + row0);
    ushort4* dst = (ushort4*)xs;
    #pragma unroll
    for (int it = 0; it < 16; ++it) dst[it*256 + tid] = f4bf(src[it*256 + tid]);
  }

  float acc[16][4];
  #pragma unroll
  for (int t = 0; t < 16; ++t){
    #pragma unroll
    for (int c = 0; c < 4; ++c) acc[t][c] = 0.f;
  }

  for (int h = 0; h < HC; ++h){
    // ---- q, k, v for this head ----
    for (int which = 0; which < 3; ++which){
      __syncthreads();  // protect wtile region reuse (also covers xs after load, first iter)
      const int cbase = h*96 + which*32;
      #pragma unroll
      for (int it = 0; it < 8; ++it){
        int id = it*256 + tid;           // 2048 4-elem units = 256x32
        int k = id >> 3;
        int j4 = (id & 7) << 2;
        float4 wv4 = *(const float4*)(qkvw + (size_t)k*(3*DIMC) + cbase + j4);
        ((ushort4*)wtile)[id] = f4bf(wv4);
      }
      __syncthreads();
      u16* ob = qb + which*(WC*34);
      const int j = tid & 31, tq = tid >> 5;
      float a[8];
      float bias = qkvb[cbase + j];
      #pragma unroll
      for (int i = 0; i < 8; ++i) a[i] = bias;
      #pragma unroll 4
      for (int k = 0; k < DIMC; ++k){
        float w = bf2f(wtile[k*32 + j]);
        #pragma unroll
        for (int i = 0; i < 8; ++i)
          a[i] += bf2f(xs[(tq*8+i)*DIMC + k]) * w;
      }
      #pragma unroll
      for (int i = 0; i < 8; ++i) ob[(tq*8+i)*34 + j] = f2bf(a[i]);
    }
    __syncthreads();
    // ---- S = q k^T * scale (wave wv owns rows wv*16..wv*16+15, lane = col) ----
    {
      float kr[32];
      #pragma unroll
      for (int d = 0; d < 32; ++d) kr[d] = bf2f(kb[lane*34 + d]);
      #pragma unroll 2
      for (int ii = 0; ii < 16; ++ii){
        int i = wv*16 + ii;
        float a = 0.f;
        #pragma unroll
        for (int d = 0; d < 32; ++d) a += bf2f(qb[i*34 + d]) * kr[d];
        Sb[i*64 + lane] = a * 0.17677669529663687f;  // 1/sqrt(32)
      }
    }
    // ---- softmax over k (same wave owns its rows) ----
    {
      #pragma unroll 2
      for (int ii = 0; ii < 16; ++ii){
        int i = wv*16 + ii;
        float v = Sb[i*64 + lane];
        float mx = v;
        #pragma unroll
        for (int o = 32; o; o >>= 1) mx = fmaxf(mx, __shfl_xor(mx, o));
        float e = __expf(v - mx);
        float sm = e;
        #pragma unroll
        for (int o = 32; o; o >>= 1) sm += __shfl_xor(sm, o);
        Sb[i*64 + lane] = e / sm;
      }
    }
    __syncthreads();
    // ---- O = P V (writes Oh over q,k region; all waves past S by now) ----
    {
      const int d = tid & 31, grp = tid >> 5;
      #pragma unroll
      for (int ii = 0; ii < 8; ++ii){
        int i = grp*8 + ii;
        float a = 0.f;
        #pragma unroll 4
        for (int j = 0; j < WC; ++j)
          a += Sb[i*64 + j] * bf2f(vb[j*34 + d]);
        Oh[i*32 + d] = a;
      }
    }
    __syncthreads();
    // ---- stage proj_w rows for this head (32 x 256), fp32 -> bf16 LDS ----
    #pragma unroll
    for (int it = 0; it < 8; ++it){
      int id = it*256 + tid;
      float4 wv4 = *(const float4*)(projw + (size_t)h*32*DIMC + id*4);
      ((ushort4*)wtile)[id] = f4bf(wv4);
    }
    __syncthreads();
    // ---- accumulate proj: acc[t][cb] += Oh[t][d] * w[d][cb*64+lane] ----
    {
      #pragma unroll 4
      for (int d = 0; d < 32; ++d){
        float w0 = bf2f(wtile[d*256 + lane]);
        float w1 = bf2f(wtile[d*256 + 64 + lane]);
        float w2 = bf2f(wtile[d*256 + 128 + lane]);
        float w3 = bf2f(wtile[d*256 + 192 + lane]);
        #pragma unroll
        for (int t = 0; t < 16; ++t){
          float o = Oh[(wv*16 + t)*32 + d];
          acc[t][0] += o*w0;
          acc[t][1] += o*w1;
          acc[t][2] += o*w2;
          acc[t][3] += o*w3;
        }
      }
    }
  }
  // epilogue: h = x_hat(fp32 from global) + attn_proj + proj_b  -> overwrite rows in Y
  {
    float pb0 = projb[lane];
    float pb1 = projb[64 + lane];
    float pb2 = projb[128 + lane];
    float pb3 = projb[192 + lane];
    #pragma unroll
    for (int t = 0; t < 16; ++t){
      int tok = wv*16 + t;
      long long base = row0 + (long long)tok*DIMC;
      float r0 = Y[base + lane];
      float r1 = Y[base + 64 + lane];
      float r2 = Y[base + 128 + lane];
      float r3 = Y[base + 192 + lane];
      Y[base + lane]       = r0 + acc[t][0] + pb0;
      Y[base + 64 + lane]  = r1 + acc[t][1] + pb1;
      Y[base + 128 + lane] = r2 + acc[t][2] + pb2;
      Y[base + 192 + lane] = r3 + acc[t][3] + pb3;
    }
  }
}

// ------------- K3: per-window fused LN2 + fc1 + gelu + fc2 + residual -------------
__global__ __launch_bounds__(256) void k_mlp(const int* __restrict__ idx,
    const float* __restrict__ g2, const float* __restrict__ b2,
    const float* __restrict__ w1, const float* __restrict__ b1,
    const float* __restrict__ w2, const float* __restrict__ fc2b,
    float* __restrict__ Y){
  __shared__ __align__(16) u16 hb[WC*DIMC];   // 32 KB: bf16 LN2(h)
  __shared__ __align__(16) u16 wt[8192];      // 16 KB weight tile
  __shared__ __align__(16) u16 gbuf[WC*DHC];  // 4 KB gelu chunk (64x32)

  const int tid = threadIdx.x;
  const int lane = tid & 63;
  const int wv = tid >> 6;
  const int m = blockIdx.x;
  const long long row0 = (long long)idx[m] * (WC * DIMC);

  // residual + fc2 bias in fp32 registers (read straight from global)
  float acc[16][4];
  {
    float bb0 = fc2b[lane], bb1 = fc2b[64+lane];
    float bb2v = fc2b[128+lane], bb3 = fc2b[192+lane];
    #pragma unroll
    for (int t = 0; t < 16; ++t){
      long long base = row0 + (long long)(wv*16 + t)*DIMC;
      acc[t][0] = Y[base + lane] + bb0;
      acc[t][1] = Y[base + 64 + lane] + bb1;
      acc[t][2] = Y[base + 128 + lane] + bb2v;
      acc[t][3] = Y[base + 192 + lane] + bb3;
    }
  }
  // LN2 in fp32 from global, store bf16 to LDS (wave wv owns tokens wv*16..+15)
  {
    float4 gu = ((const float4*)g2)[lane];
    float4 bu = ((const float4*)b2)[lane];
    for (int t = 0; t < 16; ++t){
      int tok = wv*16 + t;
      float4 v = ((const float4*)(Y + row0 + (long long)tok*DIMC))[lane];
      float s = v.x+v.y+v.z+v.w;
      #pragma unroll
      for (int o = 32; o; o >>= 1) s += __shfl_xor(s, o);
      float mu = s*(1.f/256.f);
      float d0=v.x-mu,d1=v.y-mu,d2=v.z-mu,d3=v.w-mu;
      float q = d0*d0+d1*d1+d2*d2+d3*d3;
      #pragma unroll
      for (int o = 32; o; o >>= 1) q += __shfl_xor(q, o);
      float rs = rsqrtf(q*(1.f/256.f)+1e-5f);
      ushort4 ou;
      ou.x = f2bf(d0*rs*gu.x+bu.x); ou.y = f2bf(d1*rs*gu.y+bu.y);
      ou.z = f2bf(d2*rs*gu.z+bu.z); ou.w = f2bf(d3*rs*gu.w+bu.w);
      ((ushort4*)hb)[tok*64 + lane] = ou;
    }
  }
  __syncthreads();

  for (int ch = 0; ch < 32; ++ch){
    // fc1 tile: 256 x 32 columns [ch*32, ch*32+32), fp32 -> bf16 LDS
    #pragma unroll
    for (int it = 0; it < 8; ++it){
      int id = it*256 + tid;
      int k = id >> 3, j4 = (id & 7) << 2;
      float4 wv4 = *(const float4*)(w1 + (size_t)k*HIDC + ch*32 + j4);
      ((ushort4*)wt)[id] = f4bf(wv4);
    }
    __syncthreads();
    {
      const int j = tid & 31, tq = tid >> 5;
      float a[8];
      float bias = b1[ch*32 + j];
      #pragma unroll
      for (int i = 0; i < 8; ++i) a[i] = bias;
      #pragma unroll 4
      for (int k = 0; k < DIMC; ++k){
        float w = bf2f(wt[k*32 + j]);
        #pragma unroll
        for (int i = 0; i < 8; ++i)
          a[i] += bf2f(hb[(tq*8+i)*DIMC + k]) * w;
      }
      #pragma unroll
      for (int i = 0; i < 8; ++i){
        float xg = a[i];
        float ge = 0.5f*xg*(1.f + erff(xg*0.70710678118654752f));
        gbuf[(tq*8+i)*32 + j] = f2bf(ge);
      }
    }
    __syncthreads();
    // fc2 tile: rows [ch*32, ch*32+32) x 256, fp32 -> bf16 LDS
    #pragma unroll
    for (int it = 0; it < 8; ++it){
      int id = it*256 + tid;
      float4 wv4 = *(const float4*)(w2 + (size_t)(ch*32)*DIMC + id*4);
      ((ushort4*)wt)[id] = f4bf(wv4);
    }
    __syncthreads();
    {
      #pragma unroll 4
      for (int jj = 0; jj < 32; ++jj){
        float w0 = bf2f(wt[jj*256 + lane]);
        float w1v = bf2f(wt[jj*256 + 64 + lane]);
        float w2v = bf2f(wt[jj*256 + 128 + lane]);
        float w3v = bf2f(wt[jj*256 + 192 + lane]);
        #pragma unroll
        for (int t = 0; t < 16; ++t){
          float gv = bf2f(gbuf[(wv*16+t)*32 + jj]);
          acc[t][0] += gv*w0; acc[t][1] += gv*w1v;
          acc[t][2] += gv*w2v; acc[t][3] += gv*w3v;
        }
      }
    }
    __syncthreads();
  }
  #pragma unroll
  for (int t = 0; t < 16; ++t){
    int tok = wv*16 + t;
    long long base = row0 + (long long)tok*DIMC;
    Y[base + lane]       = acc[t][0];
    Y[base + 64 + lane]  = acc[t][1];
    Y[base + 128 + lane] = acc[t][2];
    Y[base + 192 + lane] = acc[t][3];
  }
}

extern "C" void kernel_launch(void* const* d_in, const int* in_sizes, int n_in,
                              void* d_out, int out_size, void* d_ws, size_t ws_size,
                              hipStream_t stream) {
  const float* x    = (const float*)d_in[0];
  const int*   idx  = (const int*)d_in[1];
  const int    M    = in_sizes[1];           // index count == M
  const float* n1g  = (const float*)d_in[3];
  const float* n1b  = (const float*)d_in[4];
  const float* qkvw = (const float*)d_in[5];
  const float* qkvb = (const float*)d_in[6];
  const float* pw   = (const float*)d_in[7];
  const float* pb   = (const float*)d_in[8];
  const float* n2g  = (const float*)d_in[9];
  const float* n2b  = (const float*)d_in[10];
  const float* w1   = (const float*)d_in[11];
  const float* b1   = (const float*)d_in[12];
  const float* w2   = (const float*)d_in[13];
  const float* b2   = (const float*)d_in[14];
  float* out = (float*)d_out;
  const int ntok = out_size / DIMC;          // N*W

  k_ln1<<<(ntok + 3) / 4, 256, 0, stream>>>(x, n1g, n1b, out, ntok);
  k_attn<<<M, 256, 0, stream>>>(idx, qkvw, qkvb, pw, pb, out);
  k_mlp<<<M, 256, 0, stream>>>(idx, n2g, n2b, w1, b1, w2, b2, out);
}

// Round 3
// 1550.369 us; speedup vs baseline: 5.3444x; 5.3444x over previous
//
#include <hip/hip_runtime.h>
#include <math.h>

typedef unsigned short u16;
typedef __attribute__((ext_vector_type(8))) short bfrag;   // 8 bf16 (4 VGPRs)
typedef __attribute__((ext_vector_type(4))) float f32x4;   // 4 fp32 acc

#define MFMA(a,b,c) __builtin_amdgcn_mfma_f32_16x16x32_bf16((a),(b),(c),0,0,0)

#define DIMC 256
#define WC 64
#define HC 8
#define HIDC 1024
// ws layout (u16 element offsets)
#define OFF_QKVWT 0         // [768][256]
#define OFF_PROJWT 196608   // [256][256]
#define OFF_W1T   262144    // [1024][256]
#define OFF_W2T   524288    // [256][1024]

__device__ __forceinline__ float bf2f(u16 u){
  unsigned int i = ((unsigned int)u) << 16; float f; __builtin_memcpy(&f,&i,4); return f;
}
__device__ __forceinline__ u16 f2bf(float f){
  unsigned int i; __builtin_memcpy(&i,&f,4);
  i += 0x7FFFu + ((i >> 16) & 1u); return (u16)(i >> 16);
}

// ---------- K0: weight transpose+cast fp32 -> bf16 [out_col][k] in d_ws ----------
__global__ __launch_bounds__(256) void k_prep(const float* __restrict__ qkvw,
    const float* __restrict__ projw, const float* __restrict__ w1,
    const float* __restrict__ w2, u16* __restrict__ ws){
  int gid = blockIdx.x*256 + threadIdx.x;
  if (gid < 196608){                       // qkvwt[j][k] = qkvw[k][j]
    int j = gid >> 8, k = gid & 255;
    ws[OFF_QKVWT + gid] = f2bf(qkvw[(size_t)k*768 + j]);
  } else if (gid < 262144){                // projwt
    int g = gid - 196608; int j = g >> 8, k = g & 255;
    ws[OFF_PROJWT + g] = f2bf(projw[(size_t)k*256 + j]);
  } else if (gid < 524288){                // w1t
    int g = gid - 262144; int j = g >> 8, k = g & 255;
    ws[OFF_W1T + g] = f2bf(w1[(size_t)k*1024 + j]);
  } else {                                 // w2t[j][k] = w2[k][j], j<256,k<1024
    int g = gid - 524288; int j = g >> 10, k = g & 1023;
    ws[OFF_W2T + g] = f2bf(w2[(size_t)k*256 + j]);
  }
}

// ---------------- K1: LayerNorm1 over all tokens (fp32 -> fp32 d_out) ----------------
__global__ __launch_bounds__(256) void k_ln1(const float* __restrict__ x,
                                             const float* __restrict__ g,
                                             const float* __restrict__ b,
                                             float* __restrict__ out, int ntok){
  const int lane = threadIdx.x & 63;
  const int wv = threadIdx.x >> 6;
  const long long t = (long long)blockIdx.x * 4 + wv;
  if (t >= ntok) return;
  float4 v = ((const float4*)(x + t * DIMC))[lane];
  float s = v.x + v.y + v.z + v.w;
  #pragma unroll
  for (int o = 32; o; o >>= 1) s += __shfl_xor(s, o);
  float mu = s * (1.0f/256.0f);
  float d0 = v.x-mu, d1 = v.y-mu, d2 = v.z-mu, d3 = v.w-mu;
  float q = d0*d0 + d1*d1 + d2*d2 + d3*d3;
  #pragma unroll
  for (int o = 32; o; o >>= 1) q += __shfl_xor(q, o);
  float rs = rsqrtf(q * (1.0f/256.0f) + 1e-5f);
  float4 gv = ((const float4*)g)[lane];
  float4 bv = ((const float4*)b)[lane];
  float4 ov;
  ov.x = d0*rs*gv.x + bv.x; ov.y = d1*rs*gv.y + bv.y;
  ov.z = d2*rs*gv.z + bv.z; ov.w = d3*rs*gv.w + bv.w;
  ((float4*)(out + t * DIMC))[lane] = ov;
}

// ------------- K2: per-window MFMA qkv + attention + proj + residual -------------
__global__ __launch_bounds__(256) void k_attn(const int* __restrict__ idx,
    const u16* __restrict__ qkvwt, const float* __restrict__ qkvb,
    const u16* __restrict__ projwt, const float* __restrict__ projb,
    float* __restrict__ Y){
  __shared__ __align__(16) u16 smem[32768];      // 65536 B exactly
  u16* xs = smem;                  // [64][264] x-hat bf16
  u16* wt = smem + 16896;          // [32][264] qkv weight tile; alias Pb [64][72]
  u16* qb = smem + 16896 + 8448;   // [64][40]  (alias Ob)
  u16* kb = qb + 2560;             // [64][40]
  u16* vt = kb + 2560;             // [32][72]  v transposed [d][token]

  const int tid = threadIdx.x, lane = tid & 63, w = tid >> 6;
  const int quad = lane >> 4, l16 = lane & 15;
  const long long row0 = (long long)idx[blockIdx.x] * (WC * DIMC);
  const f32x4 z = {0.f,0.f,0.f,0.f};

  // xs: read fp32 X rows, store bf16 (wave w: tokens 16w..16w+15)
  #pragma unroll
  for (int t = 0; t < 16; ++t){
    int tok = 16*w + t;
    float4 v = ((const float4*)(Y + row0 + (long long)tok*DIMC))[lane];
    ushort4 o; o.x=f2bf(v.x); o.y=f2bf(v.y); o.z=f2bf(v.z); o.w=f2bf(v.w);
    *(ushort4*)(xs + tok*264 + lane*4) = o;
  }

  f32x4 accP[16];
  #pragma unroll
  for (int nt = 0; nt < 16; ++nt) accP[nt] = z;

  for (int h = 0; h < HC; ++h){
    // ---- q,k,v via MFMA (staged weight tiles) ----
    for (int which = 0; which < 3; ++which){
      __syncthreads();
      const int cb = h*96 + which*32;
      #pragma unroll
      for (int it = 0; it < 4; ++it){
        int id = it*256 + tid;
        int r = id >> 5, c8 = id & 31;
        *(uint4*)(wt + r*264 + c8*8) = *(const uint4*)(qkvwt + (size_t)(cb+r)*256 + c8*8);
      }
      __syncthreads();
      f32x4 c0 = z, c1 = z;
      #pragma unroll
      for (int ks = 0; ks < 8; ++ks){
        bfrag a  = *(const bfrag*)(xs + (l16+16*w)*264 + ks*32 + quad*8);
        bfrag b0 = *(const bfrag*)(wt + l16*264       + ks*32 + quad*8);
        bfrag b1 = *(const bfrag*)(wt + (l16+16)*264  + ks*32 + quad*8);
        c0 = MFMA(a, b0, c0); c1 = MFMA(a, b1, c1);
      }
      float bi0 = qkvb[cb + l16], bi1 = qkvb[cb + 16 + l16];
      if (which < 2){
        u16* dst = which ? kb : qb;
        #pragma unroll
        for (int r = 0; r < 4; ++r){
          int row = quad*4 + r + 16*w;
          dst[row*40 + l16]      = f2bf(c0[r] + bi0);
          dst[row*40 + 16 + l16] = f2bf(c1[r] + bi1);
        }
      } else {
        #pragma unroll
        for (int r = 0; r < 4; ++r){
          int row = quad*4 + r + 16*w;
          vt[l16*72 + row]      = f2bf(c0[r] + bi0);
          vt[(16+l16)*72 + row] = f2bf(c1[r] + bi1);
        }
      }
    }
    __syncthreads();
    // ---- S = q k^T (K=32, one MFMA step; wave w owns m-tile w) ----
    bfrag aq = *(const bfrag*)(qb + (l16+16*w)*40 + quad*8);
    f32x4 s[4];
    #pragma unroll
    for (int nt = 0; nt < 4; ++nt){
      bfrag bk = *(const bfrag*)(kb + (l16+16*nt)*40 + quad*8);
      s[nt] = MFMA(aq, bk, z);
    }
    // ---- softmax in C-layout registers (row = quad*4+r+16w, 16-lane groups) ----
    float p[4][4];
    #pragma unroll
    for (int r = 0; r < 4; ++r){
      const float SC = 0.17677669529663687f;
      float v0 = s[0][r]*SC, v1 = s[1][r]*SC, v2 = s[2][r]*SC, v3 = s[3][r]*SC;
      float mx = fmaxf(fmaxf(v0,v1), fmaxf(v2,v3));
      #pragma unroll
      for (int o = 1; o <= 8; o <<= 1) mx = fmaxf(mx, __shfl_xor(mx, o));
      float e0 = __expf(v0-mx), e1 = __expf(v1-mx), e2 = __expf(v2-mx), e3 = __expf(v3-mx);
      float sm = e0+e1+e2+e3;
      #pragma unroll
      for (int o = 1; o <= 8; o <<= 1) sm += __shfl_xor(sm, o);
      float inv = 1.0f / sm;
      p[0][r]=e0*inv; p[1][r]=e1*inv; p[2][r]=e2*inv; p[3][r]=e3*inv;
    }
    // ---- P -> LDS (A-layout source), aliases wt (qkv tile dead) ----
    u16* Pb = wt;
    #pragma unroll
    for (int nt = 0; nt < 4; ++nt)
      #pragma unroll
      for (int r = 0; r < 4; ++r)
        Pb[(quad*4 + r + 16*w)*72 + l16 + 16*nt] = f2bf(p[nt][r]);
    __syncthreads();
    // ---- O = P V (K=64 -> 2 ksteps) ----
    f32x4 o0 = z, o1 = z;
    #pragma unroll
    for (int ks = 0; ks < 2; ++ks){
      bfrag ap  = *(const bfrag*)(Pb + (l16+16*w)*72 + ks*32 + quad*8);
      bfrag bv0 = *(const bfrag*)(vt + l16*72      + ks*32 + quad*8);
      bfrag bv1 = *(const bfrag*)(vt + (16+l16)*72 + ks*32 + quad*8);
      o0 = MFMA(ap, bv0, o0); o1 = MFMA(ap, bv1, o1);
    }
    u16* Ob = qb;  // q dead after S
    #pragma unroll
    for (int r = 0; r < 4; ++r){
      int row = quad*4 + r + 16*w;
      Ob[row*40 + l16]      = f2bf(o0[r]);
      Ob[row*40 + 16 + l16] = f2bf(o1[r]);
    }
    __syncthreads();
    // ---- proj accumulate: B-frags direct from global projwt (L2-resident) ----
    bfrag ao = *(const bfrag*)(Ob + (l16+16*w)*40 + quad*8);
    #pragma unroll
    for (int nt = 0; nt < 16; ++nt){
      bfrag bp = *(const bfrag*)(projwt + (size_t)(l16+16*nt)*256 + h*32 + quad*8);
      accP[nt] = MFMA(ao, bp, accP[nt]);
    }
  }
  // epilogue: Y += accP + projb (residual X already in Y, fp32)
  #pragma unroll
  for (int nt = 0; nt < 16; ++nt){
    int col = l16 + 16*nt;
    float pbv = projb[col];
    #pragma unroll
    for (int r = 0; r < 4; ++r){
      int row = quad*4 + r + 16*w;
      long long a = row0 + (long long)row*DIMC + col;
      Y[a] = Y[a] + accP[nt][r] + pbv;
    }
  }
}

// ------------- K3: per-window MFMA LN2 + fc1 + gelu + fc2 + residual -------------
__global__ __launch_bounds__(256) void k_mlp(const int* __restrict__ idx,
    const float* __restrict__ g2, const float* __restrict__ b2,
    const u16* __restrict__ w1t, const float* __restrict__ b1,
    const u16* __restrict__ w2t, const float* __restrict__ fc2b,
    float* __restrict__ Y){
  __shared__ __align__(16) u16 hb[WC*264];   // 33792 B: LN2(h) bf16
  __shared__ __align__(16) u16 gb[WC*40];    // 5120 B: gelu chunk [64][40]

  const int tid = threadIdx.x, lane = tid & 63, w = tid >> 6;
  const int quad = lane >> 4, l16 = lane & 15;
  const long long row0 = (long long)idx[blockIdx.x] * (WC * DIMC);
  const f32x4 z = {0.f,0.f,0.f,0.f};

  // acc init: residual h (fp32 from Y) + fc2 bias, in C-layout (wave w: nt w*4..w*4+3)
  f32x4 acc[4][4];  // [mt][i]
  #pragma unroll
  for (int mt = 0; mt < 4; ++mt)
    #pragma unroll
    for (int i = 0; i < 4; ++i){
      int col = l16 + 16*(w*4 + i);
      float bb = fc2b[col];
      f32x4 a;
      #pragma unroll
      for (int r = 0; r < 4; ++r)
        a[r] = Y[row0 + (long long)(quad*4 + r + 16*mt)*DIMC + col] + bb;
      acc[mt][i] = a;
    }
  // LN2 -> hb bf16 (wave w: tokens 16w..16w+15)
  {
    float4 gv = ((const float4*)g2)[lane];
    float4 bv = ((const float4*)b2)[lane];
    for (int t = 0; t < 16; ++t){
      int tok = 16*w + t;
      float4 v = ((const float4*)(Y + row0 + (long long)tok*DIMC))[lane];
      float s = v.x+v.y+v.z+v.w;
      #pragma unroll
      for (int o = 32; o; o >>= 1) s += __shfl_xor(s, o);
      float mu = s*(1.f/256.f);
      float d0=v.x-mu,d1=v.y-mu,d2=v.z-mu,d3=v.w-mu;
      float q = d0*d0+d1*d1+d2*d2+d3*d3;
      #pragma unroll
      for (int o = 32; o; o >>= 1) q += __shfl_xor(q, o);
      float rs = rsqrtf(q*(1.f/256.f)+1e-5f);
      ushort4 ou;
      ou.x=f2bf(d0*rs*gv.x+bv.x); ou.y=f2bf(d1*rs*gv.y+bv.y);
      ou.z=f2bf(d2*rs*gv.z+bv.z); ou.w=f2bf(d3*rs*gv.w+bv.w);
      *(ushort4*)(hb + tok*264 + lane*4) = ou;
    }
  }
  __syncthreads();

  for (int ch = 0; ch < 32; ++ch){
    // fc1: wave covers nt = w&1 (16 cols) x m-tiles {2*(w>>1), +1}; B direct from global
    const int colL = l16 + 16*(w & 1);
    const int gcol = ch*32 + colL;
    const int m0 = (w >> 1)*2;
    f32x4 f1[2] = {z, z};
    const u16* bp = w1t + (size_t)gcol*256;
    #pragma unroll
    for (int ks = 0; ks < 8; ++ks){
      bfrag bw = *(const bfrag*)(bp + ks*32 + quad*8);
      #pragma unroll
      for (int mm = 0; mm < 2; ++mm){
        bfrag am = *(const bfrag*)(hb + (l16+16*(m0+mm))*264 + ks*32 + quad*8);
        f1[mm] = MFMA(am, bw, f1[mm]);
      }
    }
    float bias = b1[gcol];
    #pragma unroll
    for (int mm = 0; mm < 2; ++mm)
      #pragma unroll
      for (int r = 0; r < 4; ++r){
        float xg = f1[mm][r] + bias;
        float ge = 0.5f*xg*(1.f + erff(xg*0.70710678118654752f));
        gb[(quad*4 + r + 16*(m0+mm))*40 + colL] = f2bf(ge);
      }
    __syncthreads();
    // fc2: K=32 (1 kstep); A from gb, B direct from global w2t
    bfrag av[4];
    #pragma unroll
    for (int mt = 0; mt < 4; ++mt)
      av[mt] = *(const bfrag*)(gb + (l16+16*mt)*40 + quad*8);
    #pragma unroll
    for (int i = 0; i < 4; ++i){
      int nt = w*4 + i;
      bfrag bw2 = *(const bfrag*)(w2t + (size_t)(l16+16*nt)*1024 + ch*32 + quad*8);
      #pragma unroll
      for (int mt = 0; mt < 4; ++mt)
        acc[mt][i] = MFMA(av[mt], bw2, acc[mt][i]);
    }
    __syncthreads();
  }
  // epilogue
  #pragma unroll
  for (int mt = 0; mt < 4; ++mt)
    #pragma unroll
    for (int i = 0; i < 4; ++i){
      int col = l16 + 16*(w*4 + i);
      #pragma unroll
      for (int r = 0; r < 4; ++r)
        Y[row0 + (long long)(quad*4 + r + 16*mt)*DIMC + col] = acc[mt][i][r];
    }
}

extern "C" void kernel_launch(void* const* d_in, const int* in_sizes, int n_in,
                              void* d_out, int out_size, void* d_ws, size_t ws_size,
                              hipStream_t stream) {
  const float* x    = (const float*)d_in[0];
  const int*   idx  = (const int*)d_in[1];
  const int    M    = in_sizes[1];
  const float* n1g  = (const float*)d_in[3];
  const float* n1b  = (const float*)d_in[4];
  const float* qkvw = (const float*)d_in[5];
  const float* qkvb = (const float*)d_in[6];
  const float* pw   = (const float*)d_in[7];
  const float* pb   = (const float*)d_in[8];
  const float* n2g  = (const float*)d_in[9];
  const float* n2b  = (const float*)d_in[10];
  const float* w1   = (const float*)d_in[11];
  const float* b1   = (const float*)d_in[12];
  const float* w2   = (const float*)d_in[13];
  const float* b2   = (const float*)d_in[14];
  float* out = (float*)d_out;
  u16* ws = (u16*)d_ws;
  const int ntok = out_size / DIMC;

  k_prep<<<3072, 256, 0, stream>>>(qkvw, pw, w1, w2, ws);
  k_ln1<<<(ntok + 3) / 4, 256, 0, stream>>>(x, n1g, n1b, out, ntok);
  k_attn<<<M, 256, 0, stream>>>(idx, ws + OFF_QKVWT, qkvb, ws + OFF_PROJWT, pb, out);
  k_mlp<<<M, 256, 0, stream>>>(idx, n2g, n2b, ws + OFF_W1T, b1, ws + OFF_W2T, b2, out);
}